// Round 2
// 109.563 us; speedup vs baseline: 1.0096x; 1.0096x over previous
//
#include <hip/hip_runtime.h>
#include <hip/hip_bf16.h>

typedef unsigned short ushort_t;
typedef unsigned int uint_t;

#define CIN   128
#define COUT  256
#define HH    56
#define WW    56
#define HWSZ  3136            // 56*56
#define BATCH 16
#define NPIX  50176           // 16*3136
#define KTOT  1152            // 128*9

// LDS input patch: 4 pixel-rows (y0-1..y0+2) x 58 x-cols (halo) x 128 ci.
// ci-stride = 136 ushorts (68 uints): keeps 16B alignment (136%8==0) and spreads
// banks (272B/row -> bank stride 4 -> b128 reads hit the 8-cyc floor, no extra conflict).
#define PROW_U 68             // uints per (pr,x) cell row of ci
#define PATCH_U (4 * 58 * 68) // 15776 uints = 63104 B

typedef __attribute__((ext_vector_type(8))) short bf16x8;
typedef __attribute__((ext_vector_type(4))) float f32x4;

__device__ __forceinline__ ushort_t f2bf(float v) {
    union { float f; uint_t u; } c; c.f = v;
    uint_t u = c.u;
    u += 0x7FFFu + ((u >> 16) & 1u);   // RNE; inputs finite
    return (ushort_t)(u >> 16);
}

__device__ __forceinline__ uint_t pk2bf(float lo, float hi) {
    __hip_bfloat162 h = __float22bfloat162_rn(make_float2(lo, hi));  // x->low ushort
    union { __hip_bfloat162 h; uint_t u; } c; c.h = h;
    return c.u;
}

// ---- weight prep: OIHW fp32 -> A2 fragment-order table (one co per block).
// A2[((mt*36+s)*4+i)*64 + quad*16 + l16] (ushort8) = W[co=mt*64+i*16+l16][k=s*32+quad*8..+8],
// k in (pos,ci) order. conv reads A frags as coalesced global dwordx4 (L2-resident 0.59MB).
__global__ __launch_bounds__(256) void wprep(
    const float* __restrict__ weights, ushort_t* __restrict__ A2)
{
    __shared__ ushort_t lds_s[KTOT];
    const int tid = threadIdx.x;
    const int co  = blockIdx.x;
    const float* src = weights + (size_t)co * KTOT;
    #pragma unroll
    for (int k = 0; k < 5; ++k) {
        int idx = tid + k * 256;
        if (idx < KTOT) {
            int ci  = idx / 9;
            int pos = idx - ci * 9;
            lds_s[pos * 128 + ci] = f2bf(src[idx]);   // coalesced fp32 read
        }
    }
    __syncthreads();
    int mt  = co >> 6;
    int ii  = (co >> 4) & 3;
    int l16 = co & 15;
    if (tid < 144) {
        int s    = tid >> 2;
        int quad = tid & 3;
        uint4 v = *(const uint4*)&lds_s[(s >> 2) * 128 + (s & 3) * 32 + quad * 8];
        *(uint4*)(A2 + ((size_t)((mt * 36 + s) * 4 + ii) * 64 + quad * 16 + l16) * 8) = v;
    }
}

// ---- direct conv: block = 256co x 112pix (2 rows of one image), 4 waves (64co x 112pix).
// Prologue: halo-only LDS zeroing (disjoint from staged cells -> no pre-stage barrier),
// fp32->bf16 stage of the 4-row input patch, one barrier, then a fully-unrolled,
// BARRIER-FREE 36-step K-loop: triple-buffered (depth-2) global A-frag stream +
// ds_read_b128 B-frags + setprio-wrapped MFMA cluster.
__global__ __launch_bounds__(256, 2) void conv_direct(
    const ushort_t* __restrict__ A2,
    const float* __restrict__ tensor,
    const float* __restrict__ bias,
    float* __restrict__ out)
{
    __shared__ __align__(16) uint_t patch[PATCH_U];
    const int tid  = threadIdx.x;
    const int wave = tid >> 6;
    const int lane = tid & 63;
    const int quad = lane >> 4;
    const int l16  = lane & 15;

    // XCD-aware swizzle: 448 blocks % 8 XCDs == 0 -> bijective chunk map.
    // Each XCD gets 56 consecutive bn (2 images' worth), all co-resident
    // (64 block slots/XCD) -> overlapped input rows + A2 hit in that XCD's L2.
    const int bn0 = blockIdx.x;
    const int bn  = (bn0 & 7) * 56 + (bn0 >> 3);
    const int b   = bn / 28;
    const int y0  = (bn - b * 28) * 2;    // first output row of this block

    // ---- halo-only zero-fill (cells staging never writes; no barrier needed
    //      before staging since writes are disjoint) ----
    uint4* p4 = (uint4*)patch;
    if (tid < 136) {                      // x = 0 and x = 57 columns, all 4 rows
        int pr   = tid / 34;
        int r    = tid - pr * 34;
        int side = r / 17;
        int k    = r - side * 17;
        int x    = side ? 57 : 0;
        p4[(pr * 58 + x) * 17 + k] = make_uint4(0u, 0u, 0u, 0u);
    }
    if (y0 == 0) {                        // y = -1 row: zero cells x=1..56 of pr=0
        for (int g = tid; g < 952; g += 256)
            p4[17 + g] = make_uint4(0u, 0u, 0u, 0u);
    }
    if (y0 == 54) {                       // y = 57 row: zero cells x=1..56 of pr=3
        for (int g = tid; g < 952; g += 256)
            p4[2975 + g] = make_uint4(0u, 0u, 0u, 0u);
    }

    // ---- stage input rows y0-1..y0+2 (fp32 NCHW -> bf16 patch) ----
    // task: pr=row (wave-uniform per it), cp=ci-pair, xq=x-quad; 14 consecutive lanes
    // read 224B contiguous (coalesced); packed cvt -> 4 ds_write_b32.
    const float* src_b = tensor + (size_t)b * CIN * HWSZ;
    #pragma unroll
    for (int it = 0; it < 16; ++it) {
        int xq = tid & 15;
        int t2 = it * 16 + (tid >> 4);    // [0,256)
        int cp = t2 & 63;
        int pr = t2 >> 6;
        int y  = y0 - 1 + pr;
        if (xq < 14 && (uint_t)y < (uint_t)HH) {
            const float* s0 = src_b + (size_t)(2 * cp) * HWSZ + y * WW + xq * 4;
            float4 va = *(const float4*)s0;
            float4 vb = *(const float4*)(s0 + HWSZ);
            uint_t* dst = &patch[(pr * 58 + xq * 4 + 1) * PROW_U + cp];
            dst[0 * PROW_U] = pk2bf(va.x, vb.x);
            dst[1 * PROW_U] = pk2bf(va.y, vb.y);
            dst[2 * PROW_U] = pk2bf(va.z, vb.z);
            dst[3 * PROW_U] = pk2bf(va.w, vb.w);
        }
    }
    __syncthreads();      // the ONLY barrier in the kernel

    // ---- B-fragment LDS bases (halo-corner per j; quad ci-offset folded in) ----
    const ushort_t* patch_s = (const ushort_t*)patch;
    int bbase[7];
    #pragma unroll
    for (int j = 0; j < 7; ++j) {
        int p  = j * 16 + l16;            // block-local pixel [0,112)
        int ro = p / 56;
        int x  = p - ro * 56;
        bbase[j] = (ro * 58 + x) * 136 + quad * 8;   // ushort idx
    }

    // ---- A fragment stream (global, register triple-buffer = depth-2 prefetch).
    // L2 load latency ~200-300cy > one K-step (~140cy); depth-1 prefetch stalled
    // every step on vmcnt. With buf[(s+2)%3] loaded at step s, data is ~2 steps old
    // at consumption -> latency covered. All indices compile-time (full unroll).
    const ushort_t* aBase = A2 + ((size_t)(wave * 144) * 64 + lane) * 8;
    bf16x8 aBuf[3][4];
    #pragma unroll
    for (int i = 0; i < 4; ++i) aBuf[0][i] = *(const bf16x8*)(aBase + i * 512);
    #pragma unroll
    for (int i = 0; i < 4; ++i) aBuf[1][i] = *(const bf16x8*)(aBase + 2048 + i * 512);
    const ushort_t* aPtr = aBase + 2 * 2048;   // points at step s+2 data

    const f32x4 zero = {0.f, 0.f, 0.f, 0.f};
    f32x4 acc[4][7];
    #pragma unroll
    for (int i = 0; i < 4; ++i)
        #pragma unroll
        for (int j = 0; j < 7; ++j) acc[i][j] = zero;

    #pragma unroll
    for (int pos = 0; pos < 9; ++pos) {
        const int dy = pos / 3 - 1;
        const int dx = pos % 3 - 1;
        const int poff = ((dy + 1) * 58 + (dx + 1)) * 136;   // compile-time, >=0
        #pragma unroll
        for (int cc = 0; cc < 4; ++cc) {
            const int s = pos * 4 + cc;
            if (s + 2 < 36) {             // prefetch step s+2 into buf[(s+2)%3]
                #pragma unroll
                for (int i = 0; i < 4; ++i)
                    aBuf[(s + 2) % 3][i] = *(const bf16x8*)(aPtr + i * 512);
                aPtr += 2048;             // advance one k32-step (4096 B)
            }
            bf16x8 bfr[7];
            #pragma unroll
            for (int j = 0; j < 7; ++j)
                bfr[j] = *(const bf16x8*)&patch_s[bbase[j] + poff + cc * 32];
            __builtin_amdgcn_s_setprio(1);
            #pragma unroll
            for (int i = 0; i < 4; ++i)
                #pragma unroll
                for (int j = 0; j < 7; ++j)
                    acc[i][j] = __builtin_amdgcn_mfma_f32_16x16x32_bf16(
                        aBuf[s % 3][i], bfr[j], acc[i][j], 0, 0, 0);
            __builtin_amdgcn_s_setprio(0);
        }
    }

    // ---- epilogue: row(quad*4+r)=cout, col(l16)=pixel (x-contiguous 64B segments) ----
    int opix[7];
    #pragma unroll
    for (int j = 0; j < 7; ++j) {
        int p  = j * 16 + l16;
        int ro = p / 56;
        int x  = p - ro * 56;
        opix[j] = (y0 + ro) * WW + x;
    }
    const size_t bout = (size_t)b * (COUT * HWSZ);
    #pragma unroll
    for (int i = 0; i < 4; ++i) {
        #pragma unroll
        for (int r = 0; r < 4; ++r) {
            int co = wave * 64 + i * 16 + quad * 4 + r;
            float bv = bias[co];
            size_t obase = bout + (size_t)co * HWSZ;
            #pragma unroll
            for (int j = 0; j < 7; ++j)
                out[obase + opix[j]] = acc[i][j][r] + bv;
        }
    }
}

// ---- fallback (only if workspace is too small): direct fp32 conv
__global__ void naive_conv(const float* __restrict__ in, const float* __restrict__ w,
                           const float* __restrict__ bias, float* __restrict__ out, int total) {
    int idx = blockIdx.x * 256 + threadIdx.x;
    if (idx >= total) return;
    int x = idx % WW; int t = idx / WW;
    int y = t % HH; t /= HH;
    int co = t % COUT; int b = t / COUT;
    float s = bias[co];
    const float* wr = w + (size_t)co * KTOT;
    for (int ci = 0; ci < CIN; ++ci) {
        const float* ir = in + (size_t)(b * CIN + ci) * HWSZ;
        for (int kh = 0; kh < 3; ++kh) {
            int yy = y + kh - 1;
            if ((uint_t)yy >= (uint_t)HH) continue;
            for (int kw = 0; kw < 3; ++kw) {
                int xx = x + kw - 1;
                if ((uint_t)xx >= (uint_t)WW) continue;
                s += ir[yy * WW + xx] * wr[ci * 9 + kh * 3 + kw];
            }
        }
    }
    out[idx] = s;
}

extern "C" void kernel_launch(void* const* d_in, const int* in_sizes, int n_in,
                              void* d_out, int out_size, void* d_ws, size_t ws_size,
                              hipStream_t stream) {
    const float* tensor  = (const float*)d_in[0];
    const float* weights = (const float*)d_in[1];
    const float* bias    = (const float*)d_in[2];
    float* out = (float*)d_out;

    const size_t A2_BYTES = (size_t)COUT * KTOT * 2;   // 589824

    if (ws_size >= A2_BYTES) {
        ushort_t* A2 = (ushort_t*)d_ws;
        wprep<<<COUT, 256, 0, stream>>>(weights, A2);
        conv_direct<<<NPIX / 112, 256, 0, stream>>>(A2, tensor, bias, out);
    } else {
        int total = BATCH * COUT * HWSZ;
        naive_conv<<<(total + 255) / 256, 256, 0, stream>>>(tensor, weights, bias, out, total);
    }
}